// Round 2
// baseline (4059.044 us; speedup 1.0000x reference)
//
#include <hip/hip_runtime.h>
#include <hip/hip_bf16.h>

// Problem constants
#define NN 1024          // nodes
#define BB 64            // batch
#define CI 32            // c_in
#define LL 12            // seq len
#define CO 64            // c_out
#define EMB 10
#define XSZ 25165824     // B*CI*NN*LL
#define NL 12288         // NN*LL  (stride between channels)
#define BSTRIDE 393216   // CI*NN*LL (stride between batches)

// workspace offsets (floats)
#define OFF_Y1 0u
#define OFF_Y2 25165824u
#define OFF_G  50331648u
#define OFF_WN 75497472u   // [1024][3][32][32]
#define OFF_BN 78643200u   // [1024][32]
#define OFF_NE 78675968u   // [1024][10]

// ---------------------------------------------------------------------------
// node_emb[n][d] = sum_m a0[n][m]*W_ne[d][m] + b_ne[d]
__global__ __launch_bounds__(256) void k_node_emb(
    const float* __restrict__ a0, const float* __restrict__ Wne,
    const float* __restrict__ bne, float* __restrict__ ne)
{
    int gid = blockIdx.x * 256 + threadIdx.x;   // 10240 exact
    int n = gid / EMB, d = gid - n * EMB;
    const float* ar = a0 + n * NN;
    const float* wr = Wne + d * NN;
    float s = 0.f;
    for (int m = 0; m < NN; m += 4) {
        float4 av = *(const float4*)(ar + m);
        float4 wv = *(const float4*)(wr + m);
        s += av.x * wv.x + av.y * wv.y + av.z * wv.z + av.w * wv.w;
    }
    ne[gid] = s + bne[d];
}

// weights_n[n][k][i][o] = sum_d ne[n][d] * wp[d][k][i][o]
__global__ __launch_bounds__(256) void k_weights(
    const float* __restrict__ ne, const float* __restrict__ wp,
    float* __restrict__ Wn)
{
    int gid = blockIdx.x * 256 + threadIdx.x;   // 3145728 exact
    int n = gid / 3072, rest = gid - n * 3072;
    float s = 0.f;
    #pragma unroll
    for (int d = 0; d < EMB; ++d)
        s += ne[n * EMB + d] * wp[d * 3072 + rest];
    Wn[gid] = s;
}

// bias_n[n][c] = sum_d ne[n][d] * bp[d][c]
__global__ __launch_bounds__(256) void k_bias(
    const float* __restrict__ ne, const float* __restrict__ bp,
    float* __restrict__ bn)
{
    int gid = blockIdx.x * 256 + threadIdx.x;   // 32768 exact
    int n = gid >> 5, c = gid & 31;
    float s = 0.f;
    #pragma unroll
    for (int d = 0; d < EMB; ++d)
        s += ne[n * EMB + d] * bp[d * CI + c];
    bn[gid] = s;
}

// ---------------------------------------------------------------------------
// Y[bc][n][l] = sum_m A[n][m] * S[bc][m][l]        (mode 0)
// Y[bc][n][l] = 2*sum_m A[n][m]*S[bc][m][l] - X0[bc][n][l]   (mode 1)
// Tile: 64 rows (n) x (16 bc x 12 l) cols, BK=32. 256 threads, 48 acc/thread.
#define BKK 32
__global__ __launch_bounds__(256) void k_gemm(
    const float* __restrict__ A, const float* __restrict__ S,
    const float* __restrict__ X0, float* __restrict__ Y, int mode)
{
    __shared__ float As[BKK][68];     // [k][n], pad 68: aligned b128 reads
    __shared__ float Xs[16][388];     // linear chunk per bc, pad 388
    int tid = threadIdx.x;
    int bc0 = blockIdx.x * 16;        // 128 blocks
    int n0  = blockIdx.y * 64;        // 16 blocks
    int tc = tid >> 4;                // 0..15 : bc within tile
    int tr = tid & 15;                // 0..15 : row-group (4 rows each)
    int rA = tid >> 2;                // 0..63 : A load row
    int kg = (tid & 3) * 8;           // A load col group
    int bcx = tid >> 4;               // X load bc
    int cx = tid & 15;                // X load chunk lane

    float acc[4][12];
    #pragma unroll
    for (int i = 0; i < 4; ++i)
        #pragma unroll
        for (int l = 0; l < 12; ++l) acc[i][l] = 0.f;

    for (int k0 = 0; k0 < NN; k0 += BKK) {
        // global loads
        const float* ap = A + (n0 + rA) * NN + k0 + kg;
        float4 a4a = *(const float4*)ap;
        float4 a4b = *(const float4*)(ap + 4);
        const float4* xp = (const float4*)(S + (size_t)(bc0 + bcx) * NL + k0 * LL);
        float4 xv[6];
        #pragma unroll
        for (int j = 0; j < 6; ++j) xv[j] = xp[cx + 16 * j];

        __syncthreads();   // previous iter's LDS reads done
        float av[8];
        *(float4*)&av[0] = a4a; *(float4*)&av[4] = a4b;
        #pragma unroll
        for (int j = 0; j < 8; ++j) As[kg + j][rA] = av[j];
        #pragma unroll
        for (int j = 0; j < 6; ++j)
            *(float4*)&Xs[bcx][(cx + 16 * j) * 4] = xv[j];
        __syncthreads();

        #pragma unroll 4
        for (int kk = 0; kk < BKK; ++kk) {
            float4 af = *(const float4*)&As[kk][tr * 4];
            float xf[12];
            *(float4*)&xf[0] = *(const float4*)&Xs[tc][kk * 12];
            *(float4*)&xf[4] = *(const float4*)&Xs[tc][kk * 12 + 4];
            *(float4*)&xf[8] = *(const float4*)&Xs[tc][kk * 12 + 8];
            const float* afp = (const float*)&af;
            #pragma unroll
            for (int i = 0; i < 4; ++i)
                #pragma unroll
                for (int l = 0; l < 12; ++l)
                    acc[i][l] += afp[i] * xf[l];
        }
    }

    size_t base = (size_t)(bc0 + tc) * NL;
    #pragma unroll
    for (int i = 0; i < 4; ++i) {
        int n = n0 + tr * 4 + i;
        float o[12];
        if (mode == 1) {
            #pragma unroll
            for (int l = 0; l < 12; ++l)
                o[l] = 2.f * acc[i][l] - X0[base + n * 12 + l];
        } else {
            #pragma unroll
            for (int l = 0; l < 12; ++l) o[l] = acc[i][l];
        }
        *(float4*)&Y[base + n * 12 + 0] = *(float4*)&o[0];
        *(float4*)&Y[base + n * 12 + 4] = *(float4*)&o[4];
        *(float4*)&Y[base + n * 12 + 8] = *(float4*)&o[8];
    }
}

// ---------------------------------------------------------------------------
// Gather-gconv: G[m][n2][o] = bn[n2][o] + sum_{k2,c2} xg(m,k2,n2,c2)*Wn[n2][k2][c2][o]
// xg maps through the torch-faithful reshape scramble.
__global__ __launch_bounds__(256) void k_gather(
    const float* __restrict__ X, const float* __restrict__ Y1,
    const float* __restrict__ Y2, const float* __restrict__ Wn,
    const float* __restrict__ bn, float* __restrict__ G)
{
    __shared__ float Ws[3072];
    __shared__ float bs[32];
    int tid = threadIdx.x;
    int n2 = blockIdx.x;                  // 0..1023
    int m  = blockIdx.y * 256 + tid;      // 0..767

    const float4* wsrc = (const float4*)(Wn + (size_t)n2 * 3072);
    #pragma unroll
    for (int j = 0; j < 3; ++j)
        ((float4*)Ws)[tid + 256 * j] = wsrc[tid + 256 * j];
    if (tid < 8) ((float4*)bs)[tid] = ((const float4*)(bn + n2 * 32))[tid];
    __syncthreads();

    int b = m / 12, t12 = m - b * 12;
    int k = t12 >> 2, q = t12 & 3;
    const float* src = (k == 0) ? X : (k == 1 ? Y1 : Y2);
    size_t basep = (size_t)b * BSTRIDE + q * 3072;   // n = q*256 + r -> n*12 = q*3072 + r*12

    float acc[32];
    #pragma unroll
    for (int o = 0; o < 32; ++o) acc[o] = bs[o];

    for (int k2 = 0; k2 < 3; ++k2) {
        int rembase = k2 * 32768 + n2 * 32;
        #pragma unroll
        for (int c2 = 0; c2 < 32; ++c2) {
            int rem = rembase + c2;           // < 98304
            int r = rem / 384;
            int rr = rem - r * 384;
            int cc = rr / 12;
            int l = rr - cc * 12;
            float xvv = src[basep + (size_t)cc * NL + r * 12 + l];
            const float* wrow = &Ws[k2 * 1024 + c2 * 32];
            #pragma unroll
            for (int o = 0; o < 32; ++o) acc[o] += xvv * wrow[o];
        }
    }

    float* gp = G + (size_t)m * 32768 + n2 * 32;
    #pragma unroll
    for (int o = 0; o < 32; o += 4) {
        float4 v; v.x = acc[o]; v.y = acc[o+1]; v.z = acc[o+2]; v.w = acc[o+3];
        *(float4*)&gp[o] = v;
    }
}

// ---------------------------------------------------------------------------
// Final 1x1 conv, per branch s: s==0 writes (with bias), s==1 accumulates.
// out[b2][o2][pos] ; h[c3] = G flat at b2*BSTRIDE + c3*NL + pos
__global__ __launch_bounds__(256) void k_conv(
    const float* __restrict__ G, const float* __restrict__ Wmlp,
    const float* __restrict__ bmlp, float* __restrict__ out, int s)
{
    __shared__ float Ws[2048];   // [o2][32]
    __shared__ float bl[64];
    int tid = threadIdx.x;
    #pragma unroll
    for (int j = 0; j < 2; ++j) {
        int f4 = tid + 256 * j;              // 0..511
        int o2 = f4 >> 3, c4 = f4 & 7;
        ((float4*)Ws)[f4] = *(const float4*)(Wmlp + o2 * 64 + s * 32 + c4 * 4);
    }
    if (tid < 16) ((float4*)bl)[tid] = ((const float4*)bmlp)[tid];
    __syncthreads();

    int id = blockIdx.x * 256 + tid;     // 786432 exact
    int b2 = id / NL;
    int pos = id - b2 * NL;
    const float* gp = G + (size_t)b2 * BSTRIDE + pos;
    float h[32];
    #pragma unroll
    for (int c3 = 0; c3 < 32; ++c3) h[c3] = gp[(size_t)c3 * NL];

    float* op = out + (size_t)b2 * (CO * NL) + pos;
    for (int o2 = 0; o2 < 64; ++o2) {
        float a = (s == 0) ? bl[o2] : op[(size_t)o2 * NL];
        const float* wrow = &Ws[o2 * 32];
        #pragma unroll
        for (int c3 = 0; c3 < 32; ++c3) a += h[c3] * wrow[c3];
        op[(size_t)o2 * NL] = a;
    }
}

// ---------------------------------------------------------------------------
extern "C" void kernel_launch(void* const* d_in, const int* in_sizes, int n_in,
                              void* d_out, int out_size, void* d_ws, size_t ws_size,
                              hipStream_t stream)
{
    const float* x    = (const float*)d_in[0];
    const float* a0   = (const float*)d_in[1];
    const float* a1   = (const float*)d_in[2];
    const float* Wne  = (const float*)d_in[3];
    const float* bne  = (const float*)d_in[4];
    const float* wp   = (const float*)d_in[5];
    const float* bp   = (const float*)d_in[6];
    const float* Wmlp = (const float*)d_in[7];
    const float* bmlp = (const float*)d_in[8];
    float* out = (float*)d_out;

    float* ws = (float*)d_ws;
    float* Y1 = ws + OFF_Y1;
    float* Y2 = ws + OFF_Y2;
    float* G  = ws + OFF_G;
    float* Wn = ws + OFF_WN;
    float* bn = ws + OFF_BN;
    float* ne = ws + OFF_NE;

    // prologue (shared by both branches; node_emb uses a0 only)
    k_node_emb<<<40, 256, 0, stream>>>(a0, Wne, bne, ne);
    k_weights<<<12288, 256, 0, stream>>>(ne, wp, Wn);
    k_bias<<<128, 256, 0, stream>>>(ne, bp, bn);

    // branch 0 : A = a0
    k_gemm<<<dim3(128, 16), 256, 0, stream>>>(a0, x,  x, Y1, 0);
    k_gemm<<<dim3(128, 16), 256, 0, stream>>>(a0, Y1, x, Y2, 1);
    k_gather<<<dim3(1024, 3), 256, 0, stream>>>(x, Y1, Y2, Wn, bn, G);
    k_conv<<<3072, 256, 0, stream>>>(G, Wmlp, bmlp, out, 0);

    // branch 1 : A = a1
    k_gemm<<<dim3(128, 16), 256, 0, stream>>>(a1, x,  x, Y1, 0);
    k_gemm<<<dim3(128, 16), 256, 0, stream>>>(a1, Y1, x, Y2, 1);
    k_gather<<<dim3(1024, 3), 256, 0, stream>>>(x, Y1, Y2, Wn, bn, G);
    k_conv<<<3072, 256, 0, stream>>>(G, Wmlp, bmlp, out, 1);
}

// Round 4
// 1979.260 us; speedup vs baseline: 2.0508x; 2.0508x over previous
//
#include <hip/hip_runtime.h>
#include <hip/hip_bf16.h>

// Problem constants
#define NN 1024          // nodes
#define BB 64            // batch
#define CI 32            // c_in
#define LL 12            // seq len
#define CO 64            // c_out
#define EMB 10
#define NL 12288         // NN*LL  (stride between channels)
#define BSTRIDE 393216   // CI*NN*LL (stride between batches)

// workspace offsets (floats)
#define OFF_Y1  0u
#define OFF_Y2  25165824u
#define OFF_G   50331648u    // 25,165,824 f; also aliases Y1h/Y1l bf16 panels
#define OFF_XH  75497472u    // 25,165,824 bf16 = 12,582,912 f
#define OFF_XL  88080384u
#define OFF_A0H 100663296u   // 1,048,576 bf16 = 524,288 f each
#define OFF_A0L 101187584u
#define OFF_A1H 101711872u
#define OFF_A1L 102236160u
#define OFF_WN  102760448u
#define OFF_BN  105906176u
#define OFF_NE  105938944u
// total 105,949,184 floats = 423.8 MB

typedef __attribute__((ext_vector_type(8))) short short8v;
typedef __attribute__((ext_vector_type(4))) float f32x4;

__device__ __forceinline__ unsigned short f2bf(float f) {
    unsigned u = __float_as_uint(f);
    return (unsigned short)((u + 0x7FFFu + ((u >> 16) & 1u)) >> 16);
}
__device__ __forceinline__ float bf2f(unsigned short h) {
    return __uint_as_float(((unsigned)h) << 16);
}

// ---------------------------------------------------------------------------
// node_emb[n][d] = sum_m a0[n][m]*W_ne[d][m] + b_ne[d]
__global__ __launch_bounds__(256) void k_node_emb(
    const float* __restrict__ a0, const float* __restrict__ Wne,
    const float* __restrict__ bne, float* __restrict__ ne)
{
    int gid = blockIdx.x * 256 + threadIdx.x;   // 10240 exact
    int n = gid / EMB, d = gid - n * EMB;
    const float* ar = a0 + n * NN;
    const float* wr = Wne + d * NN;
    float s = 0.f;
    for (int m = 0; m < NN; m += 4) {
        float4 av = *(const float4*)(ar + m);
        float4 wv = *(const float4*)(wr + m);
        s += av.x * wv.x + av.y * wv.y + av.z * wv.z + av.w * wv.w;
    }
    ne[gid] = s + bne[d];
}

// weights_n[n][k][i][o] = sum_d ne[n][d] * wp[d][k][i][o]
__global__ __launch_bounds__(256) void k_weights(
    const float* __restrict__ ne, const float* __restrict__ wp,
    float* __restrict__ Wn)
{
    int gid = blockIdx.x * 256 + threadIdx.x;   // 3145728 exact
    int n = gid / 3072, rest = gid - n * 3072;
    float s = 0.f;
    #pragma unroll
    for (int d = 0; d < EMB; ++d)
        s += ne[n * EMB + d] * wp[d * 3072 + rest];
    Wn[gid] = s;
}

// bias_n[n][c] = sum_d ne[n][d] * bp[d][c]
__global__ __launch_bounds__(256) void k_bias(
    const float* __restrict__ ne, const float* __restrict__ bp,
    float* __restrict__ bn)
{
    int gid = blockIdx.x * 256 + threadIdx.x;   // 32768 exact
    int n = gid >> 5, c = gid & 31;
    float s = 0.f;
    #pragma unroll
    for (int d = 0; d < EMB; ++d)
        s += ne[n * EMB + d] * bp[d * CI + c];
    bn[gid] = s;
}

// ---------------------------------------------------------------------------
// Pack A (a0,a1) into bf16 hi/lo tiled images: [nt(8)][kt(32)][row(128)][k(32)]
// granule = 16B = 8 bf16 along k. image granule index g = ((nt*32+kt)*128+row)*4+slot
__global__ __launch_bounds__(256) void k_pack_a(
    const float* __restrict__ a0, const float* __restrict__ a1,
    short* __restrict__ H0h, short* __restrict__ H0l,
    short* __restrict__ H1h, short* __restrict__ H1l)
{
    int g = blockIdx.x * 256 + threadIdx.x;   // 131072 exact
    const float* src = blockIdx.y ? a1 : a0;
    short* Hh = blockIdx.y ? H1h : H0h;
    short* Hl = blockIdx.y ? H1l : H0l;
    int slot = g & 3, row = (g >> 2) & 127, panel = g >> 9;  // panel = nt*32+kt
    int kt = panel & 31, nt = panel >> 5;
    int n = nt * 128 + row;
    const float* sp = src + (size_t)n * 1024 + kt * 32 + slot * 8;
    unsigned short h[8] __attribute__((aligned(16)));
    unsigned short lo[8] __attribute__((aligned(16)));
    #pragma unroll
    for (int j = 0; j < 8; ++j) {
        float v = sp[j];
        unsigned short hh = f2bf(v);
        h[j] = hh;
        lo[j] = f2bf(v - bf2f(hh));
    }
    ((int4*)Hh)[g] = *(const int4*)h;
    ((int4*)Hl)[g] = *(const int4*)lo;
}

// Pack B-operand (x or Y1, layout [bc][m][l]) into bf16 hi/lo tiled images:
// logical B[k=m][C=bc*12+l]; image [ct(192)][kt(32)][col(128)][k(32)]
__global__ __launch_bounds__(256) void k_pack_b(
    const float* __restrict__ src, short* __restrict__ Hh, short* __restrict__ Hl)
{
    int g = blockIdx.x * 256 + threadIdx.x;   // 3,145,728 exact
    int slot = g & 3, col = (g >> 2) & 127, panel = g >> 9;  // panel = ct*32+kt
    int kt = panel & 31, ct = panel >> 5;
    int C = ct * 128 + col;
    int bc = C / 12, l = C - bc * 12;
    int k0 = kt * 32 + slot * 8;
    const float* sp = src + (size_t)bc * NL + (size_t)k0 * 12 + l;
    unsigned short h[8] __attribute__((aligned(16)));
    unsigned short lo[8] __attribute__((aligned(16)));
    #pragma unroll
    for (int j = 0; j < 8; ++j) {
        float v = sp[j * 12];
        unsigned short hh = f2bf(v);
        h[j] = hh;
        lo[j] = f2bf(v - bf2f(hh));
    }
    ((int4*)Hh)[g] = *(const int4*)h;
    ((int4*)Hl)[g] = *(const int4*)lo;
}

// ---------------------------------------------------------------------------
// MFMA GEMM: Y[n][C] = sum_k A[n][k] * B[k][C]  via 3-product bf16 split.
// Output written in [bc][n][l] layout (addr = bc*NL + n*12 + l).
// mode 0: Y = acc ; mode 1: Y = 2*acc - X0[same addr]
// Block tile 128(n) x 128(C), BK=32. 4 waves, wave tile 64x64 = 4x4 frags 16x16.
__global__ __launch_bounds__(256) void k_gemm_mfma(
    const short* __restrict__ Ah, const short* __restrict__ Al,
    const short* __restrict__ Bh, const short* __restrict__ Bl,
    float* __restrict__ Y, const float* __restrict__ X0, int mode)
{
    __shared__ short lds[4][128][40];   // Ah, Al, Bh, Bl tiles; +8 pad per row
    int tid = threadIdx.x;
    int ct = blockIdx.x, nt = blockIdx.y;
    int lane = tid & 63;
    int wid = tid >> 6;
    int RB = (wid >> 1) * 64;   // wave row base
    int CB = (wid & 1) * 64;    // wave col base
    int l15 = lane & 15, l4 = lane >> 4;

    f32x4 acc[4][4];
    #pragma unroll
    for (int mi = 0; mi < 4; ++mi)
        #pragma unroll
        for (int ni = 0; ni < 4; ++ni)
            acc[mi][ni] = (f32x4)(0.f);

    int c0 = tid >> 2, s0 = tid & 3;          // granule (col,slot) for tid
    int c1 = (tid + 256) >> 2;                // second granule (same slot)

    for (int kt = 0; kt < 32; ++kt) {
        const int4* pah = (const int4*)(Ah + (size_t)(nt * 32 + kt) * 4096);
        const int4* pal = (const int4*)(Al + (size_t)(nt * 32 + kt) * 4096);
        const int4* pbh = (const int4*)(Bh + (size_t)(ct * 32 + kt) * 4096);
        const int4* pbl = (const int4*)(Bl + (size_t)(ct * 32 + kt) * 4096);
        int4 v0 = pah[tid], v1 = pah[tid + 256];
        int4 v2 = pal[tid], v3 = pal[tid + 256];
        int4 v4 = pbh[tid], v5 = pbh[tid + 256];
        int4 v6 = pbl[tid], v7 = pbl[tid + 256];

        __syncthreads();   // previous iteration's frag reads complete
        *(int4*)&lds[0][c0][s0 * 8] = v0;  *(int4*)&lds[0][c1][s0 * 8] = v1;
        *(int4*)&lds[1][c0][s0 * 8] = v2;  *(int4*)&lds[1][c1][s0 * 8] = v3;
        *(int4*)&lds[2][c0][s0 * 8] = v4;  *(int4*)&lds[2][c1][s0 * 8] = v5;
        *(int4*)&lds[3][c0][s0 * 8] = v6;  *(int4*)&lds[3][c1][s0 * 8] = v7;
        __syncthreads();

        short8v ah[4], al[4], xh[4], xl[4];
        #pragma unroll
        for (int mi = 0; mi < 4; ++mi) {
            int r = RB + mi * 16 + l15;
            ah[mi] = *(const short8v*)&lds[0][r][l4 * 8];
            al[mi] = *(const short8v*)&lds[1][r][l4 * 8];
        }
        #pragma unroll
        for (int ni = 0; ni < 4; ++ni) {
            int c = CB + ni * 16 + l15;
            xh[ni] = *(const short8v*)&lds[2][c][l4 * 8];
            xl[ni] = *(const short8v*)&lds[3][c][l4 * 8];
        }
        #pragma unroll
        for (int mi = 0; mi < 4; ++mi)
            #pragma unroll
            for (int ni = 0; ni < 4; ++ni) {
                acc[mi][ni] = __builtin_amdgcn_mfma_f32_16x16x32_bf16(ah[mi], xh[ni], acc[mi][ni], 0, 0, 0);
                acc[mi][ni] = __builtin_amdgcn_mfma_f32_16x16x32_bf16(ah[mi], xl[ni], acc[mi][ni], 0, 0, 0);
                acc[mi][ni] = __builtin_amdgcn_mfma_f32_16x16x32_bf16(al[mi], xh[ni], acc[mi][ni], 0, 0, 0);
            }
    }

    // Epilogue: D layout col=lane&15, row=(lane>>4)*4+reg (m89-verified).
    int coff[4];
    int C0 = ct * 128 + CB + l15;
    #pragma unroll
    for (int ni = 0; ni < 4; ++ni) {
        int C = C0 + ni * 16;
        int bc = C / 12;
        int l = C - bc * 12;
        coff[ni] = bc * NL + l;
    }
    int nb = nt * 128 + RB + l4 * 4;
    #pragma unroll
    for (int mi = 0; mi < 4; ++mi) {
        #pragma unroll
        for (int r = 0; r < 4; ++r) {
            int n12 = (nb + mi * 16 + r) * 12;
            #pragma unroll
            for (int ni = 0; ni < 4; ++ni) {
                size_t addr = (size_t)coff[ni] + n12;
                float val = acc[mi][ni][r];
                if (mode == 1) val = 2.f * val - X0[addr];
                Y[addr] = val;
            }
        }
    }
}

// ---------------------------------------------------------------------------
// Gather-gconv (unchanged, validated R2): G[m][n2][o]
__global__ __launch_bounds__(256) void k_gather(
    const float* __restrict__ X, const float* __restrict__ Y1,
    const float* __restrict__ Y2, const float* __restrict__ Wn,
    const float* __restrict__ bn, float* __restrict__ G)
{
    __shared__ float Ws[3072];
    __shared__ float bs[32];
    int tid = threadIdx.x;
    int n2 = blockIdx.x;                  // 0..1023
    int m  = blockIdx.y * 256 + tid;      // 0..767

    const float4* wsrc = (const float4*)(Wn + (size_t)n2 * 3072);
    #pragma unroll
    for (int j = 0; j < 3; ++j)
        ((float4*)Ws)[tid + 256 * j] = wsrc[tid + 256 * j];
    if (tid < 8) ((float4*)bs)[tid] = ((const float4*)(bn + n2 * 32))[tid];
    __syncthreads();

    int b = m / 12, t12 = m - b * 12;
    int k = t12 >> 2, q = t12 & 3;
    const float* src = (k == 0) ? X : (k == 1 ? Y1 : Y2);
    size_t basep = (size_t)b * BSTRIDE + q * 3072;

    float acc[32];
    #pragma unroll
    for (int o = 0; o < 32; ++o) acc[o] = bs[o];

    for (int k2 = 0; k2 < 3; ++k2) {
        int rembase = k2 * 32768 + n2 * 32;
        #pragma unroll
        for (int c2 = 0; c2 < 32; ++c2) {
            int rem = rembase + c2;
            int r = rem / 384;
            int rr = rem - r * 384;
            int cc = rr / 12;
            int l = rr - cc * 12;
            float xvv = src[basep + (size_t)cc * NL + r * 12 + l];
            const float* wrow = &Ws[k2 * 1024 + c2 * 32];
            #pragma unroll
            for (int o = 0; o < 32; ++o) acc[o] += xvv * wrow[o];
        }
    }

    float* gp = G + (size_t)m * 32768 + n2 * 32;
    #pragma unroll
    for (int o = 0; o < 32; o += 4) {
        float4 v; v.x = acc[o]; v.y = acc[o+1]; v.z = acc[o+2]; v.w = acc[o+3];
        *(float4*)&gp[o] = v;
    }
}

// ---------------------------------------------------------------------------
// Final 1x1 conv (unchanged, validated R2)
__global__ __launch_bounds__(256) void k_conv(
    const float* __restrict__ G, const float* __restrict__ Wmlp,
    const float* __restrict__ bmlp, float* __restrict__ out, int s)
{
    __shared__ float Ws[2048];
    __shared__ float bl[64];
    int tid = threadIdx.x;
    #pragma unroll
    for (int j = 0; j < 2; ++j) {
        int f4 = tid + 256 * j;
        int o2 = f4 >> 3, c4 = f4 & 7;
        ((float4*)Ws)[f4] = *(const float4*)(Wmlp + o2 * 64 + s * 32 + c4 * 4);
    }
    if (tid < 16) ((float4*)bl)[tid] = ((const float4*)bmlp)[tid];
    __syncthreads();

    int id = blockIdx.x * 256 + tid;
    int b2 = id / NL;
    int pos = id - b2 * NL;
    const float* gp = G + (size_t)b2 * BSTRIDE + pos;
    float h[32];
    #pragma unroll
    for (int c3 = 0; c3 < 32; ++c3) h[c3] = gp[(size_t)c3 * NL];

    float* op = out + (size_t)b2 * (CO * NL) + pos;
    for (int o2 = 0; o2 < 64; ++o2) {
        float a = (s == 0) ? bl[o2] : op[(size_t)o2 * NL];
        const float* wrow = &Ws[o2 * 32];
        #pragma unroll
        for (int c3 = 0; c3 < 32; ++c3) a += h[c3] * wrow[c3];
        op[(size_t)o2 * NL] = a;
    }
}

// ---------------------------------------------------------------------------
extern "C" void kernel_launch(void* const* d_in, const int* in_sizes, int n_in,
                              void* d_out, int out_size, void* d_ws, size_t ws_size,
                              hipStream_t stream)
{
    const float* x    = (const float*)d_in[0];
    const float* a0   = (const float*)d_in[1];
    const float* a1   = (const float*)d_in[2];
    const float* Wne  = (const float*)d_in[3];
    const float* bne  = (const float*)d_in[4];
    const float* wp   = (const float*)d_in[5];
    const float* bp   = (const float*)d_in[6];
    const float* Wmlp = (const float*)d_in[7];
    const float* bmlp = (const float*)d_in[8];
    float* out = (float*)d_out;

    float* ws = (float*)d_ws;
    float* Y1 = ws + OFF_Y1;
    float* Y2 = ws + OFF_Y2;
    float* G  = ws + OFF_G;
    short* Gh = (short*)(ws + OFF_G);               // Y1 bf16-hi panels (alias G)
    short* Gl = (short*)(ws + OFF_G + 12582912u);   // Y1 bf16-lo panels
    short* Xh = (short*)(ws + OFF_XH);
    short* Xl = (short*)(ws + OFF_XL);
    short* A0h = (short*)(ws + OFF_A0H);
    short* A0l = (short*)(ws + OFF_A0L);
    short* A1h = (short*)(ws + OFF_A1H);
    short* A1l = (short*)(ws + OFF_A1L);
    float* Wn = ws + OFF_WN;
    float* bn = ws + OFF_BN;
    float* ne = ws + OFF_NE;

    // prologue
    k_node_emb<<<40, 256, 0, stream>>>(a0, Wne, bne, ne);
    k_weights<<<12288, 256, 0, stream>>>(ne, wp, Wn);
    k_bias<<<128, 256, 0, stream>>>(ne, bp, bn);
    k_pack_a<<<dim3(512, 2), 256, 0, stream>>>(a0, a1, A0h, A0l, A1h, A1l);
    k_pack_b<<<12288, 256, 0, stream>>>(x, Xh, Xl);

    // branch 0 : A = a0
    k_gemm_mfma<<<dim3(192, 8), 256, 0, stream>>>(A0h, A0l, Xh, Xl, Y1, x, 0);
    k_pack_b<<<12288, 256, 0, stream>>>(Y1, Gh, Gl);
    k_gemm_mfma<<<dim3(192, 8), 256, 0, stream>>>(A0h, A0l, Gh, Gl, Y2, x, 1);
    k_gather<<<dim3(1024, 3), 256, 0, stream>>>(x, Y1, Y2, Wn, bn, G);
    k_conv<<<3072, 256, 0, stream>>>(G, Wmlp, bmlp, out, 0);

    // branch 1 : A = a1
    k_gemm_mfma<<<dim3(192, 8), 256, 0, stream>>>(A1h, A1l, Xh, Xl, Y1, x, 0);
    k_pack_b<<<12288, 256, 0, stream>>>(Y1, Gh, Gl);
    k_gemm_mfma<<<dim3(192, 8), 256, 0, stream>>>(A1h, A1l, Gh, Gl, Y2, x, 1);
    k_gather<<<dim3(1024, 3), 256, 0, stream>>>(x, Y1, Y2, Wn, bn, G);
    k_conv<<<3072, 256, 0, stream>>>(G, Wmlp, bmlp, out, 1);
}